// Round 3
// baseline (140.648 us; speedup 1.0000x reference)
//
#include <hip/hip_runtime.h>

namespace {
constexpr int kL0      = 16384;
constexpr int kN1      = 8195;
constexpr int kN2      = 4101;
constexpr int kN3      = 2054;
constexpr int kThreads = 512;

// REC_LO[k] = DEC_LO[7-k] — DWT cA taps (k-order) AND IDWT low taps
constexpr float RLc[8] = {
     0.23037781330885523f,  0.7148465705525415f,   0.6308807679295904f,
    -0.02798376941698385f, -0.18703481171888114f,  0.030841381835986965f,
     0.032883011666982945f, -0.010597401785069032f };

// H2 = composite 2-level low-pass: H2[2k'+k] += RL[k']*RL[k]  (22 taps, stride 4)
struct H2T { float v[22]; };
constexpr H2T make_h2() {
    H2T h{};
    for (int kp = 0; kp < 8; ++kp)
        for (int k = 0; k < 8; ++k)
            h.v[2 * kp + k] += RLc[kp] * RLc[k];
    return h;
}

__device__ constexpr float RL[8] = {
     0.23037781330885523f,  0.7148465705525415f,   0.6308807679295904f,
    -0.02798376941698385f, -0.18703481171888114f,  0.030841381835986965f,
     0.032883011666982945f, -0.010597401785069032f };
__device__ constexpr H2T H2 = make_h2();
} // namespace

// ext_full index j -> source index for symmetric pad-7 (the reference's [1:]
// shift is absorbed into the 2n+1 correlation offset — verified R1/R2).
__device__ __forceinline__ int symidx(int j, int N) {
    if (j < 7) return 6 - j;
    int i = j - 7;
    return (i < N) ? i : (2 * N - 1 - i);
}

__global__ void __launch_bounds__(kThreads, 8)
wavelet_kernel(const float* __restrict__ x, float* __restrict__ out, int rows) {
    __shared__ float bufA[kN2 + 1];   // a2 -> la2   (4102 floats)
    __shared__ float bufB[kN3];       // a3          (2054 floats)

    const int row = blockIdx.x;
    const int tid = threadIdx.x;
    const float* __restrict__ xr = x + (size_t)row * kL0;

    // ---- Phase A: x -> a2 (fused levels 1+2: 22-tap stride-4 interior) ----
    for (int n = tid; n < kN2; n += kThreads) {
        float s;
        if (n >= 5 && n <= 4095) {
            const float* p = xr + (4 * n - 18);          // 4n-18 even -> float2 aligned
            const float2 u  = *reinterpret_cast<const float2*>(p);
            const float4 v1 = *reinterpret_cast<const float4*>(p + 2);   // 16B aligned
            const float4 v2 = *reinterpret_cast<const float4*>(p + 6);
            const float4 v3 = *reinterpret_cast<const float4*>(p + 10);
            const float4 v4 = *reinterpret_cast<const float4*>(p + 14);
            const float4 v5 = *reinterpret_cast<const float4*>(p + 18);
            s = u.x * H2.v[0];
            s = fmaf(u.y,  H2.v[1],  s);
            s = fmaf(v1.x, H2.v[2],  s); s = fmaf(v1.y, H2.v[3],  s);
            s = fmaf(v1.z, H2.v[4],  s); s = fmaf(v1.w, H2.v[5],  s);
            s = fmaf(v2.x, H2.v[6],  s); s = fmaf(v2.y, H2.v[7],  s);
            s = fmaf(v2.z, H2.v[8],  s); s = fmaf(v2.w, H2.v[9],  s);
            s = fmaf(v3.x, H2.v[10], s); s = fmaf(v3.y, H2.v[11], s);
            s = fmaf(v3.z, H2.v[12], s); s = fmaf(v3.w, H2.v[13], s);
            s = fmaf(v4.x, H2.v[14], s); s = fmaf(v4.y, H2.v[15], s);
            s = fmaf(v4.z, H2.v[16], s); s = fmaf(v4.w, H2.v[17], s);
            s = fmaf(v5.x, H2.v[18], s); s = fmaf(v5.y, H2.v[19], s);
            s = fmaf(v5.z, H2.v[20], s); s = fmaf(v5.w, H2.v[21], s);
        } else {
            // boundary: exact 2-step path with symmetric extension at both levels
            s = 0.f;
            #pragma unroll
            for (int kp = 0; kp < 8; ++kp) {
                const int m = symidx(2 * n + 1 + kp, kN1);
                float a1v = 0.f;
                #pragma unroll
                for (int k = 0; k < 8; ++k)
                    a1v = fmaf(xr[symidx(2 * m + 1 + k, kL0)], RL[k], a1v);
                s = fmaf(a1v, RL[kp], s);
            }
        }
        bufA[n] = s;
    }
    __syncthreads();

    // ---- Phase B: a2 -> a3 (standard 8-tap sym DWT over N2=4101) ----
    for (int n = tid; n < kN3; n += kThreads) {
        const int base = 2 * n + 1;
        float sa = 0.f;
        if (base >= 7 && base < kN2) {
            const float* p = bufA + (base - 7);
            #pragma unroll
            for (int k = 0; k < 8; ++k) sa = fmaf(p[k], RL[k], sa);
        } else {
            #pragma unroll
            for (int k = 0; k < 8; ++k) sa = fmaf(bufA[symidx(base + k, kN2)], RL[k], sa);
        }
        bufB[n] = sa;
    }
    __syncthreads();

    // ---- Phase C: a3 -> la2 (4102 written, first 4101 consumed) ----
    for (int i = tid; i < kN3 - 3; i += kThreads) {
        const float a0 = bufB[i],     a1 = bufB[i + 1],
                    a2 = bufB[i + 2], a3 = bufB[i + 3];
        bufA[2 * i]     = fmaf(a0, RL[6], fmaf(a1, RL[4], fmaf(a2, RL[2], a3 * RL[0])));
        bufA[2 * i + 1] = fmaf(a0, RL[7], fmaf(a1, RL[5], fmaf(a2, RL[3], a3 * RL[1])));
    }
    __syncthreads();

    // ---- Phase D: la2 -> (la1 on the fly) -> low; high = x - low ----
    float* __restrict__ lowp  = out + (size_t)row * kL0;
    float* __restrict__ highp = out + (size_t)rows * kL0 + (size_t)row * kL0;
    for (int w = tid; w < kL0 / 4; w += kThreads) {
        const float b0 = bufA[w],     b1 = bufA[w + 1], b2 = bufA[w + 2],
                    b3 = bufA[w + 3], b4 = bufA[w + 4], b5 = bufA[w + 5];
        // la1[2w .. 2w+4]
        const float e0 = fmaf(b0, RL[6], fmaf(b1, RL[4], fmaf(b2, RL[2], b3 * RL[0])));
        const float o0 = fmaf(b0, RL[7], fmaf(b1, RL[5], fmaf(b2, RL[3], b3 * RL[1])));
        const float e1 = fmaf(b1, RL[6], fmaf(b2, RL[4], fmaf(b3, RL[2], b4 * RL[0])));
        const float o1 = fmaf(b1, RL[7], fmaf(b2, RL[5], fmaf(b3, RL[3], b4 * RL[1])));
        const float e2 = fmaf(b2, RL[6], fmaf(b3, RL[4], fmaf(b4, RL[2], b5 * RL[0])));
        // low[4w .. 4w+3]
        const float s0 = fmaf(e0, RL[6], fmaf(o0, RL[4], fmaf(e1, RL[2], o1 * RL[0])));
        const float s1 = fmaf(e0, RL[7], fmaf(o0, RL[5], fmaf(e1, RL[3], o1 * RL[1])));
        const float s2 = fmaf(o0, RL[6], fmaf(e1, RL[4], fmaf(o1, RL[2], e2 * RL[0])));
        const float s3 = fmaf(o0, RL[7], fmaf(e1, RL[5], fmaf(o1, RL[3], e2 * RL[1])));
        const float4 xv = reinterpret_cast<const float4*>(xr)[w];
        reinterpret_cast<float4*>(lowp)[w]  = make_float4(s0, s1, s2, s3);
        reinterpret_cast<float4*>(highp)[w] = make_float4(xv.x - s0, xv.y - s1,
                                                          xv.z - s2, xv.w - s3);
    }
}

extern "C" void kernel_launch(void* const* d_in, const int* in_sizes, int n_in,
                              void* d_out, int out_size, void* d_ws, size_t ws_size,
                              hipStream_t stream) {
    (void)n_in; (void)d_ws; (void)ws_size; (void)out_size;
    const float* x = (const float*)d_in[0];
    float* out = (float*)d_out;
    const int rows = in_sizes[0] / kL0;   // 2048
    hipLaunchKernelGGL(wavelet_kernel, dim3(rows), dim3(kThreads), 0, stream,
                       x, out, rows);
}

// Round 4
// 108.020 us; speedup vs baseline: 1.3020x; 1.3020x over previous
//
#include <hip/hip_runtime.h>

namespace {
constexpr int kL0      = 16384;
constexpr int kN1      = 8195;
constexpr int kN2      = 4101;
constexpr int kTS      = 2048;              // low/high outputs per tile
constexpr int kTilesPerRow = kL0 / kTS;     // 8
constexpr int kThreads = 256;

// LDS tile sizes (exact, derived from dependency ranges; verified at edges)
constexpr int SX  = 2138;   // xext  [O-42 , O+2096)
constexpr int SA1 = 1066;   // a1ext [O/2-18, O/2+1048)
constexpr int SA2 = 530;    // a2ext [O/4-6 , O/4+524)
constexpr int SA3 = 262;    // a3    [O/8   , O/8+262)
constexpr int SL2 = 517;    // la2   [O/4   , O/4+517)

// REC_LO[k] = DEC_LO[7-k] — DWT cA taps (k-order) AND IDWT low taps
__device__ constexpr float RL[8] = {
     0.23037781330885523f,  0.7148465705525415f,   0.6308807679295904f,
    -0.02798376941698385f, -0.18703481171888114f,  0.030841381835986965f,
     0.032883011666982945f, -0.010597401785069032f };
} // namespace

// half-sample symmetric reflection (pywt 'symmetric'); single fold suffices here
__device__ __forceinline__ int reflect(int g, int N) {
    if (g < 0)  g = -1 - g;
    if (g >= N) g = 2 * N - 1 - g;
    return g;
}

__device__ __forceinline__ float tap8(const float* __restrict__ p) {
    float s = p[0] * RL[0];
    s = fmaf(p[1], RL[1], s); s = fmaf(p[2], RL[2], s);
    s = fmaf(p[3], RL[3], s); s = fmaf(p[4], RL[4], s);
    s = fmaf(p[5], RL[5], s); s = fmaf(p[6], RL[6], s);
    s = fmaf(p[7], RL[7], s);
    return s;
}

__global__ void __launch_bounds__(kThreads, 8)
wavelet_tiled(const float* __restrict__ x, float* __restrict__ out, int rows) {
    __shared__ float sx [SX];
    __shared__ float sa1[SA1];
    __shared__ float sa2[SA2];
    __shared__ float sa3[SA3];
    __shared__ float sl2[SL2];

    const int tid  = threadIdx.x;
    const int row  = blockIdx.x / kTilesPerRow;
    const int tile = blockIdx.x % kTilesPerRow;
    const int O  = tile * kTS;
    const int X0 = O - 42;          // global x index of sx[0]
    const int A0 = O / 2 - 18;      // global a1 index of sa1[0]
    const int B0 = O / 4 - 6;       // global a2 index of sa2[0]
    const float* __restrict__ xr = x + (size_t)row * kL0;

    // ---- stage x slice (x-level symmetric reflection folded into the load) ----
    for (int t = tid; t < SX; t += kThreads)
        sx[t] = xr[reflect(X0 + t, kL0)];
    __syncthreads();

    // ---- a1 tile: sa1[m] = a1ext[A0+m];  a1[n] = sum_k xext[2n-6+k]*RL[k] ----
    for (int m = tid; m < SA1; m += kThreads) {
        const int ng = reflect(A0 + m, kN1);        // a1-level reflection
        sa1[m] = tap8(&sx[2 * (ng - A0)]);
    }
    __syncthreads();

    // ---- a2 tile: sa2[m] = a2ext[B0+m];  a2[n] = sum_k a1ext[2n-6+k]*RL[k] ----
    for (int m = tid; m < SA2; m += kThreads) {
        const int ng = reflect(B0 + m, kN2);        // a2-level reflection
        sa2[m] = tap8(&sa1[2 * (ng - B0)]);
    }
    __syncthreads();

    // ---- a3 tile (indices always interior at a3 level) ----
    for (int m = tid; m < SA3; m += kThreads)
        sa3[m] = tap8(&sa2[2 * m]);
    __syncthreads();

    // ---- la2 tile: sl2[v] = la2[O/4+v] (O/4 even, so parity(v)=parity(j)) ----
    for (int v = tid; v < SL2; v += kThreads) {
        const float* a = &sa3[v >> 1];
        float s;
        if (v & 1)
            s = fmaf(a[0], RL[7], fmaf(a[1], RL[5], fmaf(a[2], RL[3], a[3] * RL[1])));
        else
            s = fmaf(a[0], RL[6], fmaf(a[1], RL[4], fmaf(a[2], RL[2], a[3] * RL[0])));
        sl2[v] = s;
    }
    __syncthreads();

    // ---- final: la2 -> (la1 on the fly) -> low; high = x - low ----
    float* __restrict__ lowp  = out + (size_t)row * kL0 + O;
    float* __restrict__ highp = out + (size_t)rows * kL0 + (size_t)row * kL0 + O;
    for (int u = tid; u < kTS / 4; u += kThreads) {
        const float b0 = sl2[u],     b1 = sl2[u + 1], b2 = sl2[u + 2],
                    b3 = sl2[u + 3], b4 = sl2[u + 4], b5 = sl2[u + 5];
        // la1[O/2+2u .. O/2+2u+4]
        const float e0 = fmaf(b0, RL[6], fmaf(b1, RL[4], fmaf(b2, RL[2], b3 * RL[0])));
        const float o0 = fmaf(b0, RL[7], fmaf(b1, RL[5], fmaf(b2, RL[3], b3 * RL[1])));
        const float e1 = fmaf(b1, RL[6], fmaf(b2, RL[4], fmaf(b3, RL[2], b4 * RL[0])));
        const float o1 = fmaf(b1, RL[7], fmaf(b2, RL[5], fmaf(b3, RL[3], b4 * RL[1])));
        const float e2 = fmaf(b2, RL[6], fmaf(b3, RL[4], fmaf(b4, RL[2], b5 * RL[0])));
        // low[O+4u .. O+4u+3]
        const float s0 = fmaf(e0, RL[6], fmaf(o0, RL[4], fmaf(e1, RL[2], o1 * RL[0])));
        const float s1 = fmaf(e0, RL[7], fmaf(o0, RL[5], fmaf(e1, RL[3], o1 * RL[1])));
        const float s2 = fmaf(o0, RL[6], fmaf(e1, RL[4], fmaf(o1, RL[2], e2 * RL[0])));
        const float s3 = fmaf(o0, RL[7], fmaf(e1, RL[5], fmaf(o1, RL[3], e2 * RL[1])));
        const int xi = 42 + 4 * u;                    // sx index of x[O+4u]
        const float x0 = sx[xi], x1 = sx[xi + 1], x2 = sx[xi + 2], x3 = sx[xi + 3];
        reinterpret_cast<float4*>(lowp)[u]  = make_float4(s0, s1, s2, s3);
        reinterpret_cast<float4*>(highp)[u] = make_float4(x0 - s0, x1 - s1,
                                                          x2 - s2, x3 - s3);
    }
}

extern "C" void kernel_launch(void* const* d_in, const int* in_sizes, int n_in,
                              void* d_out, int out_size, void* d_ws, size_t ws_size,
                              hipStream_t stream) {
    (void)n_in; (void)d_ws; (void)ws_size; (void)out_size;
    const float* x = (const float*)d_in[0];
    float* out = (float*)d_out;
    const int rows = in_sizes[0] / kL0;                     // 2048
    const int blocks = rows * kTilesPerRow;                 // 16384
    hipLaunchKernelGGL(wavelet_tiled, dim3(blocks), dim3(kThreads), 0, stream,
                       x, out, rows);
}

// Round 5
// 101.902 us; speedup vs baseline: 1.3802x; 1.0600x over previous
//
#include <hip/hip_runtime.h>

namespace {
constexpr int kL0      = 16384;
constexpr int kN1      = 8195;
constexpr int kN2      = 4101;
constexpr int kTS      = 2048;              // outputs per tile
constexpr int kTilesPerRow = kL0 / kTS;     // 8
constexpr int kThreads = 256;

// LDS tile sizes (exact dependency ranges; verified at both row edges)
constexpr int SX  = 2138;   // xext  [O-42 , O+2096)
constexpr int SA1 = 1066;   // a1ext [O/2-18, O/2+1048)
constexpr int SA2 = 530;    // a2ext [O/4-6 , O/4+524)
constexpr int SA3 = 262;    // a3    [O/8   , O/8+262)

constexpr float RLc[8] = {
     0.23037781330885523f,  0.7148465705525415f,   0.6308807679295904f,
    -0.02798376941698385f, -0.18703481171888114f,  0.030841381835986965f,
     0.032883011666982945f, -0.010597401785069032f };

// Composite 3-level low-reconstruction bank:
// low[8q+r] = sum_{m=0..6} W[r][m] * a3[q+m]
// Built by composing the verified per-level rule y[j] = sum_t a[j/2+t]*RL[6+(j&1)-2t].
struct WT { float w[8][7]; };
constexpr WT make_w() {
    WT W{};
    for (int r = 0; r < 8; ++r) {
        const int r2 = r >> 1, pi = r & 1;
        for (int u = 0; u < 4; ++u) {
            const float cu = RLc[6 + pi - 2 * u];      // la1 tap
            const int k = r2 + u, k2 = k >> 1, pk = k & 1;
            for (int s = 0; s < 4; ++s) {
                const float cs = RLc[6 + pk - 2 * s];  // la2 tap
                const int j = k2 + s, j2 = j >> 1, pj = j & 1;
                for (int t = 0; t < 4; ++t)
                    W.w[r][j2 + t] += cu * cs * RLc[6 + pj - 2 * t];
            }
        }
    }
    return W;
}

__device__ constexpr float RL[8] = {
     0.23037781330885523f,  0.7148465705525415f,   0.6308807679295904f,
    -0.02798376941698385f, -0.18703481171888114f,  0.030841381835986965f,
     0.032883011666982945f, -0.010597401785069032f };
__device__ constexpr WT W = make_w();
} // namespace

// half-sample symmetric reflection; single fold suffices for all ranges used
__device__ __forceinline__ int reflect(int g, int N) {
    if (g < 0)  g = -1 - g;
    if (g >= N) g = 2 * N - 1 - g;
    return g;
}

// 8-tap correlation with RL; p must point to an EVEN float index (8B-aligned)
__device__ __forceinline__ float tap8(const float* __restrict__ p) {
    const float2* q = reinterpret_cast<const float2*>(p);
    const float2 q0 = q[0], q1 = q[1], q2 = q[2], q3 = q[3];
    float s = q0.x * RL[0];
    s = fmaf(q0.y, RL[1], s); s = fmaf(q1.x, RL[2], s); s = fmaf(q1.y, RL[3], s);
    s = fmaf(q2.x, RL[4], s); s = fmaf(q2.y, RL[5], s); s = fmaf(q3.x, RL[6], s);
    s = fmaf(q3.y, RL[7], s);
    return s;
}

__global__ void __launch_bounds__(kThreads, 8)
wavelet_tiled(const float* __restrict__ x, float* __restrict__ out, int rows) {
    __shared__ float sx [SX];
    __shared__ float sa1[SA1];
    __shared__ float sa2[SA2];
    __shared__ float sa3[SA3];

    const int tid  = threadIdx.x;
    const int row  = blockIdx.x / kTilesPerRow;
    const int tile = blockIdx.x % kTilesPerRow;
    const int O  = tile * kTS;
    const int X0 = O - 42;          // global x index of sx[0]
    const int A0 = (O >> 1) - 18;   // global a1 index of sa1[0]
    const int B0 = (O >> 2) - 6;    // global a2 index of sa2[0]
    const float* __restrict__ xr = x + (size_t)row * kL0;

    // ---- stage x slice: float4 vector body + scalar reflected edges ----
    // t0 chosen so X0+t0 is 16B-aligned and in-range; thi = first out-of-range t.
    const int t0  = (tile == 0) ? 42 : 2;
    const int thi = (tile == kTilesPerRow - 1) ? 2090 : SX;
    const int Nv  = (thi - t0) >> 2;                 // exact multiples (534/524/522)
    for (int v = tid; v < Nv; v += kThreads) {
        const float4 val = *reinterpret_cast<const float4*>(xr + X0 + t0 + 4 * v);
        float2* dst = reinterpret_cast<float2*>(&sx[t0 + 4 * v]);   // 8B-aligned
        dst[0] = make_float2(val.x, val.y);
        dst[1] = make_float2(val.z, val.w);
    }
    for (int t = tid; t < SX; t += kThreads)
        if (t < t0 || t >= t0 + 4 * Nv)
            sx[t] = xr[reflect(X0 + t, kL0)];
    __syncthreads();

    // ---- a1 tile: sa1[m] = a1ext[A0+m] ----
    for (int m = tid; m < SA1; m += kThreads) {
        const int ng = reflect(A0 + m, kN1);
        sa1[m] = tap8(&sx[2 * (ng - A0)]);
    }
    __syncthreads();

    // ---- a2 tile: sa2[m] = a2ext[B0+m] ----
    for (int m = tid; m < SA2; m += kThreads) {
        const int ng = reflect(B0 + m, kN2);
        sa2[m] = tap8(&sa1[2 * (ng - B0)]);
    }
    __syncthreads();

    // ---- a3 tile (always interior at a3 level) ----
    for (int m = tid; m < SA3; m += kThreads)
        sa3[m] = tap8(&sa2[2 * m]);
    __syncthreads();

    // ---- final: low[8q+r] = sum_m W[r][m]*a3[q+m]; high = x - low ----
    // thread tid owns q = O/8 + tid -> outputs i = O + 8*tid + (0..7)
    float a[7];
    #pragma unroll
    for (int m = 0; m < 7; ++m) a[m] = sa3[tid + m];   // lane-stride 1: conflict-free

    float lo[8];
    #pragma unroll
    for (int r = 0; r < 8; ++r) {
        float s = a[0] * W.w[r][0];
        #pragma unroll
        for (int m = 1; m < 7; ++m) s = fmaf(a[m], W.w[r][m], s);
        lo[r] = s;
    }

    const float4* xr4 = reinterpret_cast<const float4*>(xr + O + 8 * tid);
    const float4 xv0 = xr4[0], xv1 = xr4[1];           // L2-hot re-read, coalesced
    float* __restrict__ lowp  = out + (size_t)row * kL0 + O + 8 * tid;
    float* __restrict__ highp = lowp + (size_t)rows * kL0;
    reinterpret_cast<float4*>(lowp)[0]  = make_float4(lo[0], lo[1], lo[2], lo[3]);
    reinterpret_cast<float4*>(lowp)[1]  = make_float4(lo[4], lo[5], lo[6], lo[7]);
    reinterpret_cast<float4*>(highp)[0] = make_float4(xv0.x - lo[0], xv0.y - lo[1],
                                                      xv0.z - lo[2], xv0.w - lo[3]);
    reinterpret_cast<float4*>(highp)[1] = make_float4(xv1.x - lo[4], xv1.y - lo[5],
                                                      xv1.z - lo[6], xv1.w - lo[7]);
}

extern "C" void kernel_launch(void* const* d_in, const int* in_sizes, int n_in,
                              void* d_out, int out_size, void* d_ws, size_t ws_size,
                              hipStream_t stream) {
    (void)n_in; (void)d_ws; (void)ws_size; (void)out_size;
    const float* x = (const float*)d_in[0];
    float* out = (float*)d_out;
    const int rows = in_sizes[0] / kL0;                     // 2048
    const int blocks = rows * kTilesPerRow;                 // 16384
    hipLaunchKernelGGL(wavelet_tiled, dim3(blocks), dim3(kThreads), 0, stream,
                       x, out, rows);
}